// Round 5
// baseline (26.186 us; speedup 1.0000x reference)
//
#include <hip/hip_runtime.h>

// Analytic construction of the 4 Floquet TBC Hamiltonians for NX=64, NY=32.
// Site s = y*64 + x  (x in [0,64), y in [0,32)).
// H1 (k=0): vertical (x,y)-(x,y+1), (x+y) even; y-wrap at x odd,  theta_y
// H2 (k=1): horizontal (x,y)-(x+1,y), x<=62, (x+y) odd; x-wrap (63,y even)->(0,y), theta_x
// H3 (k=2): vertical, (x+y) odd; y-wrap at x even, theta_y
// H4 (k=3): horizontal, (x+y) even, x<=62; wrap (63,y odd)->(0,y-1), theta_x
// Wrap bond (a,b): H[a,b] = -exp(+i th), H[b,a] = -exp(-i th). Interior: -1.
//
// The harness buffer holds out_size float32s. For out_size = 4*2048*2048 the
// comparison reference is the complex64 tensor cast to float32 (= REAL part).
// Real part: interior -1; wrap cells -cos(theta) in both directions.

// Cell classification: 0 = zero, 1 = -1, 2 = -exp(+i th), 3 = -exp(-i th)
__device__ inline int cellcode(int k, int r, int c) {
    int xr = r & 63, yr = r >> 6;
    int xc = c & 63, yc = c >> 6;

    if ((k & 1) == 0) {                    // H1 / H3 : vertical bonds
        int want = (k == 0) ? 0 : 1;       // parity of the lower-index site
        if (c == r + 64 && ((xr + yr) & 1) == want) return 1;
        if (r == c + 64 && ((xc + yc) & 1) == want) return 1;
        int xpar = (k == 0) ? 1 : 0;       // wrap-bond column parity
        if (xr == xc && (xr & 1) == xpar) {
            if (yr == 31 && yc == 0) return 2;   // H[bottom-row, top-row] = -e^{+i th}
            if (yr == 0 && yc == 31) return 3;
        }
    } else {                               // H2 / H4 : horizontal bonds
        int want = (k == 1) ? 1 : 0;
        if (c == r + 1 && xr != 63 && ((xr + yr) & 1) == want) return 1;
        if (r == c + 1 && xc != 63 && ((xc + yc) & 1) == want) return 1;
        if (k == 1) {                      // wrap within even rows
            if (yr == yc && (yr & 1) == 0) {
                if (xr == 63 && xc == 0) return 2;
                if (xc == 63 && xr == 0) return 3;
            }
        } else {                           // H4 wrap: (63, y odd) -> (0, y-1)
            if (xr == 63 && (yr & 1) == 1 && xc == 0 && yc == yr - 1) return 2;
            if (xc == 63 && (yc & 1) == 1 && xr == 0 && yr == yc - 1) return 3;
        }
    }
    return 0;
}

// Real-part layout: out_size floats = 4*2048*2048 cells, one float per cell.
__global__ void build_real_kernel(float4* __restrict__ out, int n4,
                                  const float* __restrict__ theta_x,
                                  const float* __restrict__ theta_y) {
    int idx = blockIdx.x * blockDim.x + threadIdx.x;
    if (idx >= n4) return;

    int cell0 = idx << 2;                  // 4 consecutive cells, same row
    int k   = cell0 >> 22;                 // 2048*2048 = 2^22 cells per matrix
    int rem = cell0 & ((1 << 22) - 1);
    int r   = rem >> 11;
    int c0  = rem & 2047;

    int q0 = cellcode(k, r, c0);
    int q1 = cellcode(k, r, c0 + 1);
    int q2 = cellcode(k, r, c0 + 2);
    int q3 = cellcode(k, r, c0 + 3);

    float4 v;
    v.x = (q0 == 1) ? -1.f : 0.f;
    v.y = (q1 == 1) ? -1.f : 0.f;
    v.z = (q2 == 1) ? -1.f : 0.f;
    v.w = (q3 == 1) ? -1.f : 0.f;

    // Wrap cells: ~192 of 16.7M -> nearly every wave skips this uniformly.
    if ((q0 | q1 | q2 | q3) >= 2) {
        float th = (k & 1) ? theta_x[0] : theta_y[0];
        float mc = -cosf(th);              // real part of -e^{+-i th}
        if (q0 >= 2) v.x = mc;
        if (q1 >= 2) v.y = mc;
        if (q2 >= 2) v.z = mc;
        if (q3 >= 2) v.w = mc;
    }
    out[idx] = v;
}

// Fallback: interleaved complex layout (out_size floats = 2 per cell).
__global__ void build_cplx_kernel(float4* __restrict__ out, int n4,
                                  const float* __restrict__ theta_x,
                                  const float* __restrict__ theta_y) {
    int idx = blockIdx.x * blockDim.x + threadIdx.x;
    if (idx >= n4) return;

    int cell0 = idx << 1;                  // 2 complex cells
    int k   = cell0 >> 22;
    int rem = cell0 & ((1 << 22) - 1);
    int r   = rem >> 11;
    int c0  = rem & 2047;

    int q0 = cellcode(k, r, c0);
    int q1 = cellcode(k, r, c0 + 1);

    float4 v = make_float4(0.f, 0.f, 0.f, 0.f);
    if (q0 == 1) v.x = -1.f;
    if (q1 == 1) v.z = -1.f;
    if ((q0 | q1) >= 2) {
        float th = (k & 1) ? theta_x[0] : theta_y[0];
        float s = sinf(th), c = cosf(th);
        if (q0 >= 2) { v.x = -c; v.y = (q0 == 3) ? s : -s; }
        if (q1 >= 2) { v.z = -c; v.w = (q1 == 3) ? s : -s; }
    }
    out[idx] = v;
}

extern "C" void kernel_launch(void* const* d_in, const int* in_sizes, int n_in,
                              void* d_out, int out_size, void* d_ws, size_t ws_size,
                              hipStream_t stream) {
    (void)in_sizes; (void)n_in; (void)d_ws; (void)ws_size;

    const float* theta_x = (const float*)d_in[0];
    const float* theta_y = (const float*)d_in[1];

    const long long NCELL = 4LL * 2048 * 2048;   // 16,777,216 complex cells
    int n4 = out_size / 4;                        // never write past out_size
    int blocks = (n4 + 255) / 256;

    if ((long long)out_size == 2 * NCELL) {
        // interleaved complex layout (re,im per cell)
        build_cplx_kernel<<<blocks, 256, 0, stream>>>((float4*)d_out, n4,
                                                      theta_x, theta_y);
    } else {
        // one float per cell: real part of H (complex64 -> float32 cast)
        build_real_kernel<<<blocks, 256, 0, stream>>>((float4*)d_out, n4,
                                                      theta_x, theta_y);
    }
}

// Round 6
// 17.405 us; speedup vs baseline: 1.5045x; 1.5045x over previous
//
#include <hip/hip_runtime.h>

// Two-phase analytic build of the 4 Floquet TBC Hamiltonians (NX=64, NY=32),
// real-part float32 layout: out[k*2048*2048 + r*2048 + c], k in [0,4).
//
// Phase 1: hipMemsetAsync zero-fill (64 MB, runs at the pure-write ceiling).
// Phase 2: one thread per NONZERO cell (8192 total), closed-form enumeration:
//   H1 (k=0): vertical (x,y)-(x,y+1), (x+y) even; y-wrap at x odd  (theta_y)
//   H2 (k=1): horizontal (x,y)-(x+1,y), (x+y) odd;  x-wrap even rows (theta_x)
//   H3 (k=2): vertical, (x+y) odd; y-wrap at x even (theta_y)
//   H4 (k=3): horizontal, (x+y) even; wrap (63,2p+1)->(0,2p) (theta_x)
// Interior cell value: -1. Wrap cell value: Re(-e^{+-i th}) = -cos(th).
// Wrap cells never collide with interior cells (disjoint |r-c| sets), so
// write order within the scatter kernel is irrelevant.

__global__ void scatter_kernel(float* __restrict__ out,
                               const float* __restrict__ theta_x,
                               const float* __restrict__ theta_y) {
    int t = blockIdx.x * blockDim.x + threadIdx.x;   // 0..8191
    int k, row, col;
    float val = -1.f;

    if (t < 1984) {                       // H1 interior: 992 bonds x 2 dirs
        int dir = t & 1, b = t >> 1;
        int y = b >> 5, xi = b & 31;
        int x = 2 * xi + (y & 1);         // (x+y) even
        int a = y * 64 + x, c2 = a + 64;
        k = 0; row = dir ? c2 : a; col = dir ? a : c2;
    } else if (t < 3968) {                // H3 interior: 992 x 2
        int u = t - 1984;
        int dir = u & 1, b = u >> 1;
        int y = b >> 5, xi = b & 31;
        int x = 2 * xi + ((y & 1) ^ 1);   // (x+y) odd
        int a = y * 64 + x, c2 = a + 64;
        k = 2; row = dir ? c2 : a; col = dir ? a : c2;
    } else if (t < 5984) {                // H2 interior: 1008 x 2
        int u = t - 3968;
        int dir = u & 1, b = u >> 1;      // b in [0,1008)
        int p = b / 63, j = b - 63 * p;   // 63 bonds per (even,odd) row pair
        int y, x;
        if (j < 31) { y = 2 * p;     x = 2 * j + 1; }      // even row: x odd
        else        { y = 2 * p + 1; x = 2 * (j - 31); }   // odd row: x even
        int a = y * 64 + x, c2 = a + 1;
        k = 1; row = dir ? c2 : a; col = dir ? a : c2;
    } else if (t < 8000) {                // H4 interior: 1008 x 2
        int u = t - 5984;
        int dir = u & 1, b = u >> 1;
        int p = b / 63, j = b - 63 * p;
        int y, x;
        if (j < 32) { y = 2 * p;     x = 2 * j; }              // even row: x even
        else        { y = 2 * p + 1; x = 2 * (j - 32) + 1; }   // odd row: x odd
        int a = y * 64 + x, c2 = a + 1;
        k = 3; row = dir ? c2 : a; col = dir ? a : c2;
    } else {                              // wrap bonds: 96 x 2 = 192 cells
        int w = t - 8000;                 // [0,192)
        int dir = w & 1, q = w >> 1;      // q in [0,96)
        int a, b2;
        float th;
        if (q < 32) {                     // H1: (1985+2p, 1+2p), theta_y
            k = 0; a = 1985 + 2 * q; b2 = 1 + 2 * q; th = theta_y[0];
        } else if (q < 64) {              // H3: (1984+2p, 2p), theta_y
            int p = q - 32;
            k = 2; a = 1984 + 2 * p; b2 = 2 * p; th = theta_y[0];
        } else if (q < 80) {              // H2: (63+128p, 128p), theta_x
            int p = q - 64;
            k = 1; a = 63 + 128 * p; b2 = 128 * p; th = theta_x[0];
        } else {                          // H4: (127+128p, 128p), theta_x
            int p = q - 80;
            k = 3; a = 127 + 128 * p; b2 = 128 * p; th = theta_x[0];
        }
        val = -cosf(th);                  // real part, direction-independent
        row = dir ? b2 : a; col = dir ? a : b2;
    }

    out[(size_t)k * (2048 * 2048) + (size_t)row * 2048 + col] = val;
}

extern "C" void kernel_launch(void* const* d_in, const int* in_sizes, int n_in,
                              void* d_out, int out_size, void* d_ws, size_t ws_size,
                              hipStream_t stream) {
    (void)in_sizes; (void)n_in; (void)d_ws; (void)ws_size;

    const float* theta_x = (const float*)d_in[0];
    const float* theta_y = (const float*)d_in[1];

    // Phase 1: zero the whole output (out_size float32s = 64 MB).
    hipMemsetAsync(d_out, 0, (size_t)out_size * sizeof(float), stream);

    // Phase 2: scatter the 8192 nonzero cells (32 blocks x 256 threads).
    scatter_kernel<<<32, 256, 0, stream>>>((float*)d_out, theta_x, theta_y);
}

// Round 7
// 16.504 us; speedup vs baseline: 1.5866x; 1.0546x over previous
//
#include <hip/hip_runtime.h>

// Single-dispatch analytic build of the 4 Floquet TBC Hamiltonians
// (NX=64, NY=32), real-part float32 layout out[k][r][c], k in [0,4),
// r,c in [0,2048). Site s = y*64 + x.
//
// Nonzero structure (verified cell-for-cell by the R6 scatter kernel, absmax 0):
//   H1 (k=0): d=r-c = +-64, lower site (x+y) even -> -1 ; d = +-1984, x odd  -> -cos(ty)
//   H3 (k=2): d = +-64, lower site (x+y) odd  -> -1 ; d = +-1984, x even -> -cos(ty)
//   H2 (k=1): d = +-1, lower x!=63, (x+y) odd  -> -1 ; d = +-63,  low%128==0 -> -cos(tx)
//   H4 (k=3): d = +-1, lower x!=63, (x+y) even -> -1 ; d = +-127, low%128==0 -> -cos(tx)
// Everything else is 0. Each thread writes one float4 (4 cells of one row);
// the fast path (zero) needs only a per-k diagonal band test (~15 VALU insts),
// the slow path (~1.5% of threads) computes the closed-form value per cell.

__device__ inline float cellval(int k, int r, int c,
                                const float* __restrict__ tx,
                                const float* __restrict__ ty) {
    int d = r - c;
    int lo = (d > 0) ? c : r;              // lower-index site of the pair
    int x = lo & 63, y = lo >> 6;

    if ((k & 1) == 0) {                    // H1 / H3 : vertical bonds
        int want = (k == 0) ? 0 : 1;
        if (d == 64 || d == -64)
            return (((x + y) & 1) == want) ? -1.f : 0.f;
        if (d == 1984 || d == -1984) {     // y-wrap: low site in row y=0
            int xpar = (k == 0) ? 1 : 0;
            return ((x & 1) == xpar) ? -cosf(ty[0]) : 0.f;
        }
    } else {                               // H2 / H4 : horizontal bonds
        int want = (k == 1) ? 1 : 0;
        if (d == 1 || d == -1)
            return (x != 63 && ((x + y) & 1) == want) ? -1.f : 0.f;
        int wd = (k == 1) ? 63 : 127;
        if (d == wd || d == -wd)           // x-wrap: low site = 128*p
            return ((lo & 127) == 0) ? -cosf(tx[0]) : 0.f;
    }
    return 0.f;
}

__global__ void build_kernel(float4* __restrict__ out, int n4,
                             const float* __restrict__ theta_x,
                             const float* __restrict__ theta_y) {
    int idx = blockIdx.x * blockDim.x + threadIdx.x;
    if (idx >= n4) return;

    int cell0 = idx << 2;                  // 4 consecutive cells, same row
    int k   = cell0 >> 22;                 // 2048*2048 = 2^22 cells per matrix
    int rem = cell0 & ((1 << 22) - 1);
    int r   = rem >> 11;
    int c0  = rem & 2047;
    int d0  = r - c0;                      // cell i has d = d0 - i, i in [0,4)

    // Diagonal band test: does any of the 4 cells sit on a nonzero diagonal?
    // d in {D} for some i  <=>  d0 in [D, D+3]  <=>  (unsigned)(d0-D) < 4.
    bool slow;
    if ((k & 1) == 0) {
        slow = ((unsigned)(d0 - 64) < 4u)  | ((unsigned)(d0 + 64) < 4u) |
               ((unsigned)(d0 - 1984) < 4u) | ((unsigned)(d0 + 1984) < 4u);
    } else if (k == 1) {
        slow = ((unsigned)(d0 - 1) < 4u)   | ((unsigned)(d0 + 1) < 4u) |
               ((unsigned)(d0 - 63) < 4u)  | ((unsigned)(d0 + 63) < 4u);
    } else {
        slow = ((unsigned)(d0 - 1) < 4u)   | ((unsigned)(d0 + 1) < 4u) |
               ((unsigned)(d0 - 127) < 4u) | ((unsigned)(d0 + 127) < 4u);
    }

    float4 v = make_float4(0.f, 0.f, 0.f, 0.f);
    if (slow) {
        v.x = cellval(k, r, c0,     theta_x, theta_y);
        v.y = cellval(k, r, c0 + 1, theta_x, theta_y);
        v.z = cellval(k, r, c0 + 2, theta_x, theta_y);
        v.w = cellval(k, r, c0 + 3, theta_x, theta_y);
    }
    out[idx] = v;
}

extern "C" void kernel_launch(void* const* d_in, const int* in_sizes, int n_in,
                              void* d_out, int out_size, void* d_ws, size_t ws_size,
                              hipStream_t stream) {
    (void)in_sizes; (void)n_in; (void)d_ws; (void)ws_size;

    const float* theta_x = (const float*)d_in[0];
    const float* theta_y = (const float*)d_in[1];

    int n4 = out_size / 4;                 // 4,194,304 float4 stores
    int blocks = (n4 + 255) / 256;         // 16384 workgroups x 256
    build_kernel<<<blocks, 256, 0, stream>>>((float4*)d_out, n4,
                                             theta_x, theta_y);
}